// Round 12
// baseline (310.204 us; speedup 1.0000x reference)
//
#include <hip/hip_runtime.h>
#include <cstdint>
#include <cstddef>

typedef unsigned short u16;
typedef unsigned int u32;
typedef __attribute__((ext_vector_type(8))) short shortx8;
typedef __attribute__((ext_vector_type(4))) float floatx4;

#define SLICES 128
#define TWOS   (2 * SLICES)
#define F3CAP  5120

__device__ __forceinline__ u16 f2b(float f) {
    u32 b = __float_as_uint(f);
    b += 0x7fffu + ((b >> 16) & 1u);   // RNE
    return (u16)(b >> 16);
}

// ================= uprep: weight-space pushdown precompute (1 block) =================
// uw layout (floats):
//   [0,128) u31; [128,256) u32; [256] c3; [257,260) c2v;
//   [260,708) m1c[7][64]; [708,1156) m2c[7][64]; [1156,1163) C[7]
__global__ __launch_bounds__(256) void uprep(const float* __restrict__ W11, const float* __restrict__ W12,
                                             const float* __restrict__ W21, const float* __restrict__ W22,
                                             const float* __restrict__ W31, const float* __restrict__ W32,
                                             const float* __restrict__ b11, const float* __restrict__ b12,
                                             const float* __restrict__ b21, const float* __restrict__ b22,
                                             const float* __restrict__ b31, const float* __restrict__ b32,
                                             const float* __restrict__ Wr1, const float* __restrict__ Wr2,
                                             const float* __restrict__ Wr3, const float* __restrict__ br3,
                                             float* __restrict__ uw) {
    __shared__ float H[6 * 128];
    int t = threadIdx.x;
    if (t < 128) {
        float a = 0.f, b = 0.f;
        for (int c = 0; c < 64; ++c) {
            a = fmaf(W31[t * 64 + c], Wr3[c], a);
            b = fmaf(W32[t * 64 + c], Wr3[64 + c], b);
        }
        uw[t] = a;
        uw[128 + t] = b;
    }
    __syncthreads();
    for (int it = t; it < 768; it += 256) {
        int v = it >> 7;
        int k = it & 127;
        const float* W = (v < 3) ? W21 : W22;
        const float* s;
        switch (v % 3) { case 0: s = Wr2; break; case 1: s = uw; break; default: s = uw + 128; }
        int so = (v < 3) ? 0 : 64;
        float acc = 0.f;
        for (int c = 0; c < 64; ++c) acc = fmaf(W[k * 64 + c], s[so + c], acc);
        H[v * 128 + k] = acc;
    }
    __syncthreads();
    for (int it = t; it < 7 * 64; it += 256) {
        int j = it >> 6, i = it & 63;
        float a1 = 0.f, a2 = 0.f;
        if (j == 0) {
            for (int c = 0; c < 64; ++c) {
                a1 = fmaf(W11[i * 64 + c], Wr1[c], a1);
                a2 = fmaf(W12[i * 64 + c], Wr1[64 + c], a2);
            }
        } else {
            const float* h = &H[(j - 1) * 128];
            for (int c = 0; c < 64; ++c) {
                a1 = fmaf(W11[i * 64 + c], h[c], a1);
                a2 = fmaf(W12[i * 64 + c], h[64 + c], a2);
            }
        }
        uw[260 + j * 64 + i] = a1;
        uw[708 + j * 64 + i] = a2;
    }
    if (t < 64) {
        float bb1 = b11[t], bb2 = b12[t];
        float r;
#define REDW(VAL, IDX)                                                  \
        { r = (VAL);                                                    \
          for (int o = 32; o > 0; o >>= 1) r += __shfl_down(r, o);      \
          if (t == 0) uw[IDX] = r; }
        REDW(bb1 * Wr1[t] + bb2 * Wr1[64 + t], 1156)
        REDW(bb1 * H[0 * 128 + t] + bb2 * H[0 * 128 + 64 + t], 1157)
        REDW(bb1 * H[1 * 128 + t] + bb2 * H[1 * 128 + 64 + t], 1158)
        REDW(bb1 * H[2 * 128 + t] + bb2 * H[2 * 128 + 64 + t], 1159)
        REDW(bb1 * H[3 * 128 + t] + bb2 * H[3 * 128 + 64 + t], 1160)
        REDW(bb1 * H[4 * 128 + t] + bb2 * H[4 * 128 + 64 + t], 1161)
        REDW(bb1 * H[5 * 128 + t] + bb2 * H[5 * 128 + 64 + t], 1162)
        float c1 = b21[t], c2 = b22[t];
        REDW(c1 * Wr2[t] + c2 * Wr2[64 + t], 257)
        REDW(c1 * uw[t] + c2 * uw[64 + t], 258)
        REDW(c1 * uw[128 + t] + c2 * uw[192 + t], 259)
        REDW(b31[t] * Wr3[t] + b32[t] * Wr3[64 + t], 256)
        if (t == 0) uw[256] += br3[0];
#undef REDW
    }
}

// ================= histU: per-(bucket,slice) histogram + gbase init =================
__global__ __launch_bounds__(256) void histU(const int* __restrict__ ei1, const int* __restrict__ ei2,
                                             int* __restrict__ pcnt, u32* __restrict__ gbase,
                                             int NB, int E1, int E2) {
    __shared__ u32 h[512];
    int bid = blockIdx.x;
    if (bid == TWOS) {
        if (threadIdx.x == 0) *gbase = 0;
        return;
    }
    int set = bid >> 7;
    int s = bid & (SLICES - 1);
    const int* col = set ? ei2 + E2 : ei1 + E1;
    int E = set ? E2 : E1;
    for (int i = threadIdx.x; i < NB; i += 256) h[i] = 0;
    __syncthreads();
    int esz = (E + SLICES - 1) / SLICES;
    int e0 = s * esz, e1 = min(e0 + esz, E);
    for (int e = e0 + threadIdx.x; e < e1; e += 256)
        atomicAdd(&h[col[e] >> 7], 1u);
    __syncthreads();
    for (int b = threadIdx.x; b < NB; b += 256)
        pcnt[(size_t)(set * NB + b) * SLICES + s] = (int)h[b];
}

// ====== scanB: per-bucket scan of 128 slice counts + atomic region base ======
__global__ __launch_bounds__(256) void scanB(int* __restrict__ pcnt, int* __restrict__ bend,
                                             u32* __restrict__ gbase, int NBtot) {
    __shared__ int sc[SLICES];
    __shared__ u32 baseSh;
    int bid = blockIdx.x;
    if (bid >= NBtot) return;
    int t = threadIdx.x;
    int v = 0;
    if (t < SLICES) { v = pcnt[(size_t)bid * SLICES + t]; sc[t] = v; }
    __syncthreads();
    for (int off = 1; off < SLICES; off <<= 1) {
        int u = (t < SLICES && t >= off) ? sc[t - off] : 0;
        __syncthreads();
        if (t < SLICES) sc[t] += u;
        __syncthreads();
    }
    if (t == 0) {
        u32 total = (u32)sc[SLICES - 1];
        u32 base = atomicAdd(gbase, total);
        baseSh = base;
        bend[bid] = (int)(base + total);
    }
    __syncthreads();
    if (t < SLICES) pcnt[(size_t)bid * SLICES + t] = (int)(baseSh + (u32)(sc[t] - v));
}

// ================= part: bucket partition (per-(bucket,slice) LDS cursors) =================
__global__ __launch_bounds__(256) void part(const int* __restrict__ ei1, const int* __restrict__ ei2,
                                            const int* __restrict__ poffs, u32* __restrict__ eord,
                                            int NB, int E1, int E2) {
    __shared__ u32 curL[512];
    int pb = blockIdx.x;
    int set = pb >> 7;
    int s = pb & (SLICES - 1);
    const int* rows = set ? ei2 : ei1;
    int E = set ? E2 : E1;
    const int* cols = rows + E;
    for (int b = threadIdx.x; b < NB; b += 256)
        curL[b] = (u32)poffs[(size_t)(set * NB + b) * SLICES + s];
    __syncthreads();
    int esz = (E + SLICES - 1) / SLICES;
    int e0 = s * esz, e1 = min(e0 + esz, E);
    for (int e = e0 + threadIdx.x; e < e1; e += 256) {
        int c = cols[e];
        u32 pos = atomicAdd(&curL[c >> 7], 1u);
        eord[pos] = ((u32)rows[e] << 7) | (u32)(c & 127);
    }
}

// ============== mmR0: R0 MFMA + readout0 + UNSCALED source payloads (stream-2 branch) ==========
__global__ __launch_bounds__(256) void mmR0(const float* __restrict__ x,
                                            const float* __restrict__ W_in,
                                            const float* __restrict__ b_in,
                                            float* __restrict__ s1p,
                                            float* __restrict__ s2p,
                                            const float* __restrict__ Wr0,
                                            const float* __restrict__ br0,
                                            const float* __restrict__ br1,
                                            const float* __restrict__ br2,
                                            const float* __restrict__ w0,
                                            const float* __restrict__ w1,
                                            const float* __restrict__ w2,
                                            const float* __restrict__ w3,
                                            const float* __restrict__ uw,
                                            float* __restrict__ outacc, int n) {
    constexpr int LDA = 72;
    __shared__ u16 As[64 * LDA];
    __shared__ u16 W0s[64 * LDA];
    __shared__ float Msw[64][17];

    const int tid = threadIdx.x;
    const int r0 = blockIdx.x * 64;

    for (int idx = tid; idx < 64 * 16; idx += 256) {
        int r = idx >> 4, q4 = (idx & 15) * 4;
        int gr = r0 + r;
        float4 v = {0, 0, 0, 0};
        if (gr < n) v = *(const float4*)&x[(size_t)gr * 64 + q4];
        ushort4 o = {f2b(v.x), f2b(v.y), f2b(v.z), f2b(v.w)};
        *(ushort4*)&As[r * LDA + q4] = o;
    }
    for (int idx = tid; idx < 16 * 64; idx += 256) {
        int k = idx >> 4, qc = idx & 15;
        float4 a = *(const float4*)&W_in[k * 64 + 4 * qc];
        W0s[(4*qc+0) * LDA + k] = f2b(a.x); W0s[(4*qc+1) * LDA + k] = f2b(a.y);
        W0s[(4*qc+2) * LDA + k] = f2b(a.z); W0s[(4*qc+3) * LDA + k] = f2b(a.w);
    }
    for (int idx = tid; idx < 896; idx += 256) {
        int mat = idx / 448, rem = idx % 448;
        Msw[rem & 63][mat * 8 + (rem >> 6)] = uw[260 + idx];
    }
    for (int idx = tid; idx < 128; idx += 256) {
        Msw[idx & 63][(idx >> 6) * 8 + 7] = 0.f;
    }
    __syncthreads();

    const int wave = tid >> 6;
    const int lane = tid & 63;
    const int m = lane & 15;
    const int ko = (lane >> 4) * 8;
    floatx4 z4 = {0.f, 0.f, 0.f, 0.f};
    floatx4 accR[4] = {z4, z4, z4, z4};

#pragma unroll
    for (int kc = 0; kc < 64; kc += 32) {
        shortx8 af = *(shortx8*)&As[(wave * 16 + m) * LDA + kc + ko];
#pragma unroll
        for (int nt = 0; nt < 4; ++nt) {
            shortx8 bf = *(shortx8*)&W0s[(nt * 16 + m) * LDA + kc + ko];
            accR[nt] = __builtin_amdgcn_mfma_f32_16x16x32_bf16(af, bf, accR[nt], 0, 0, 0);
        }
    }

    float bv[4], wr0[4];
#pragma unroll
    for (int nt = 0; nt < 4; ++nt) {
        bv[nt] = b_in[nt * 16 + m];
        wr0[nt] = Wr0[nt * 16 + m];
    }
    const int lrow = wave * 16 + (lane >> 4) * 4;
    float W0c = w0[0];
    float CONST = W0c * br0[0] + w1[0] * (br1[0] + uw[1156]) + w2[0] * br2[0] + w3[0] * uw[256];
#pragma unroll
    for (int rg = 0; rg < 4; ++rg) {
        int gr = r0 + lrow + rg;
        float p = 0.f;
#pragma unroll
        for (int nt = 0; nt < 4; ++nt) {
            float v = fmaxf(accR[nt][rg] + bv[nt], 0.f);
            As[(lrow + rg) * LDA + nt * 16 + m] = f2b(v);   // R0 back into LDS (wave-private)
            p = fmaf(v, wr0[nt], p);
        }
#pragma unroll
        for (int off = 8; off > 0; off >>= 1) p += __shfl_down(p, off);
        if (m == 0 && gr < n) outacc[gr] = W0c * p + CONST;
    }
    // No barrier: each wave reads only its own 16 rows of As below.
    {
        int prow = lane & 15;
        int q = lane >> 4;
        int row = wave * 16 + prow;
        const int cb = (q >> 1) * 8 + (q & 1) * 4;
        float p0 = 0.f, p1 = 0.f, p2 = 0.f, p3 = 0.f;
#pragma unroll
        for (int kc = 0; kc < 64; kc += 8) {
            shortx8 rv = *(shortx8*)&As[row * LDA + kc];
#pragma unroll
            for (int tt = 0; tt < 8; ++tt) {
                float f = __uint_as_float(((u32)(u16)rv[tt]) << 16);
                p0 = fmaf(f, Msw[kc + tt][cb + 0], p0);
                p1 = fmaf(f, Msw[kc + tt][cb + 1], p1);
                p2 = fmaf(f, Msw[kc + tt][cb + 2], p2);
                p3 = fmaf(f, Msw[kc + tt][cb + 3], p3);
            }
        }
        int gr = r0 + row;
        if (gr < n) {
            float* dst = ((q < 2) ? s1p : s2p) + (size_t)gr * 8 + (q & 1) * 4;
            *(float4*)dst = make_float4(p0, p1, p2, p3);   // UNSCALED; dinv[src] in gatherP
        }
    }
}

// ================= fill3: per-bucket count/place -> se(int2), dinv, u16 csr =================
__global__ __launch_bounds__(256) void fill3(const u32* __restrict__ eord,
                                             const int* __restrict__ poffs,
                                             const int* __restrict__ bend,
                                             int2* __restrict__ se,
                                             u16* __restrict__ csr,
                                             float* __restrict__ d1, float* __restrict__ d2,
                                             int N, int NB) {
    __shared__ u32 cacheE[F3CAP];
    __shared__ u32 cnt[128];
    __shared__ int sc[128];
    __shared__ u32 cur[128];
    int bid = blockIdx.x;
    int set = bid >= NB;
    int bucket = set ? bid - NB : bid;
    if (threadIdx.x < 128) cnt[threadIdx.x] = 0;
    __syncthreads();
    int s0 = poffs[(size_t)bid * SLICES];
    int s1 = bend[bid];
    for (int j = s0 + threadIdx.x; j < s1; j += 256) {
        u32 e = eord[j];
        int o = j - s0;
        if (o < F3CAP) cacheE[o] = e;
        atomicAdd(&cnt[e & 127], 1u);
    }
    __syncthreads();
    if (threadIdx.x < 128) sc[threadIdx.x] = (int)cnt[threadIdx.x];
    __syncthreads();
    for (int off = 1; off < 128; off <<= 1) {
        int u = (threadIdx.x < 128 && threadIdx.x >= off) ? sc[threadIdx.x - off] : 0;
        __syncthreads();
        if (threadIdx.x < 128) sc[threadIdx.x] += u;
        __syncthreads();
    }
    if (threadIdx.x < 128) {
        u32 st = (u32)s0 + (u32)(sc[threadIdx.x] - (int)cnt[threadIdx.x]);  // exclusive
        cur[threadIdx.x] = st;
        int bin = bucket * 128 + threadIdx.x;
        if (bin < N) {
            se[set * N + bin] = make_int2((int)st, (int)(st + (int)cnt[threadIdx.x]));
            u32 d = cnt[threadIdx.x];
            float v = d > 0 ? rsqrtf((float)d) : 0.f;
            if (set) d2[bin] = v;
            else d1[bin] = v;
        }
    }
    __syncthreads();
    for (int j = s0 + threadIdx.x; j < s1; j += 256) {
        int o = j - s0;
        u32 e = (o < F3CAP) ? cacheE[o] : eord[j];
        u32 pos = atomicAdd(&cur[e & 127], 1u);
        csr[pos] = (u16)(e >> 7);
    }
}

// ========= gatherP: both-set payload gather + epilogue (1 dest/wave; dinv[src] per edge) =======
__global__ __launch_bounds__(256) void gatherP(const int2* __restrict__ se,
                                               const u16* __restrict__ csr,
                                               const float* __restrict__ s1p,
                                               const float* __restrict__ s2p,
                                               const float* __restrict__ dinv1,
                                               const float* __restrict__ dinv2,
                                               const float* __restrict__ uw,
                                               float4* __restrict__ sA,
                                               float4* __restrict__ sB,
                                               float* __restrict__ pr, int N) {
    int d = (blockIdx.x * blockDim.x + threadIdx.x) >> 6;
    int lane = threadIdx.x & 63;
    if (d >= N) return;
    int half = lane >> 5;
    int slot = (lane & 31) >> 1;
    int part = lane & 1;
    int base = half ? N : 0;
    int2 sg = se[base + d];
    const float* S = half ? s2p : s1p;
    const float* D = half ? dinv2 : dinv1;
    float ax = 0.f, ay = 0.f, az = 0.f, aw = 0.f;
    for (int j = sg.x + slot; j < sg.y; j += 16) {
        u32 src = csr[j];
        float w = D[src];
        float4 pv = *(const float4*)&S[(size_t)src * 8 + part * 4];
        ax = fmaf(w, pv.x, ax); ay = fmaf(w, pv.y, ay);
        az = fmaf(w, pv.z, az); aw = fmaf(w, pv.w, aw);
    }
#pragma unroll
    for (int off = 2; off <= 16; off <<= 1) {
        ax += __shfl_down(ax, off);
        ay += __shfl_down(ay, off);
        az += __shfl_down(az, off);
        aw += __shfl_down(aw, off);
    }
    float bx = __shfl(ax, lane + 32);
    float by = __shfl(ay, lane + 32);
    float bz = __shfl(az, lane + 32);
    float bw = __shfl(aw, lane + 32);
    if (lane < 2) {
        float da = dinv1[d], db = dinv2[d];
        float d0 = da * ax + db * bx;
        float d1 = da * ay + db * by;
        float d2 = da * az + db * bz;
        float d3 = da * aw + db * bw;
        const float* C = uw + 1156;
        if (lane == 0) {
            pr[d] = d0;
            sA[d] = make_float4(da * (d1 + C[1]), da * (d2 + C[2]), da * (d3 + C[3]), 0.f);
        } else {
            sB[d] = make_float4(db * (d0 + C[4]), db * (d1 + C[5]), db * (d2 + C[6]), 0.f);
        }
    }
}

// ================= gatherS: 2 destinations per wave; 16 lanes per (dest,set) =================
__global__ __launch_bounds__(256) void gatherS(const int2* __restrict__ se,
                                               const u16* __restrict__ csr,
                                               const float4* __restrict__ sA,
                                               const float4* __restrict__ sB,
                                               const float* __restrict__ pr,
                                               const float* __restrict__ dinv1,
                                               const float* __restrict__ dinv2,
                                               const float* __restrict__ w1,
                                               const float* __restrict__ w2,
                                               const float* __restrict__ w3,
                                               const float* __restrict__ c2v,
                                               float* __restrict__ outacc,
                                               float* __restrict__ z1, float* __restrict__ z2, int N) {
    int wid = (blockIdx.x * blockDim.x + threadIdx.x) >> 6;
    int lane = threadIdx.x & 63;
    int g = lane >> 5;
    int sub = lane & 31;
    int set = sub >> 4;
    int l16 = sub & 15;
    int d = wid * 2 + g;
    float p = 0.f, q1 = 0.f, q2 = 0.f;
    if (d < N) {
        int base = set ? N : 0;
        int2 sg = se[base + d];
        const float4* S = set ? sB : sA;
        for (int j = sg.x + l16; j < sg.y; j += 16) {
            float4 s = S[csr[j]];
            p += s.x; q1 += s.y; q2 += s.z;
        }
    }
#pragma unroll
    for (int off = 8; off > 0; off >>= 1) {
        p += __shfl_down(p, off); q1 += __shfl_down(q1, off); q2 += __shfl_down(q2, off);
    }
    float pB  = __shfl(p,  lane + 16);
    float qB1 = __shfl(q1, lane + 16);
    float qB2 = __shfl(q2, lane + 16);
    if (sub == 0 && d < N) {
        float da = dinv1[d], db = dinv2[d];
        float pp  = da * p  + db * pB;
        float qq1 = da * q1 + db * qB1;
        float qq2 = da * q2 + db * qB2;
        float W3 = w3[0];
        outacc[d] += w1[0] * pr[d] + w2[0] * (pp + c2v[0]);
        z1[d] = da * (W3 * (qq1 + c2v[1]));
        z2[d] = db * (W3 * (qq2 + c2v[2]));
    }
}

// ================= gather3: 2 destinations per wave; 16 lanes per (dest,set) =================
__global__ __launch_bounds__(256) void gather3(const int2* __restrict__ se,
                                               const u16* __restrict__ csr,
                                               const float* __restrict__ z1,
                                               const float* __restrict__ z2,
                                               const float* __restrict__ dinv1,
                                               const float* __restrict__ dinv2,
                                               const float* __restrict__ outacc,
                                               float* __restrict__ out, int N) {
    int wid = (blockIdx.x * blockDim.x + threadIdx.x) >> 6;
    int lane = threadIdx.x & 63;
    int g = lane >> 5;
    int sub = lane & 31;
    int set = sub >> 4;
    int l16 = sub & 15;
    int d = wid * 2 + g;
    float acc = 0.f;
    if (d < N) {
        int base = set ? N : 0;
        int2 sg = se[base + d];
        const float* Z = set ? z2 : z1;
        for (int j = sg.x + l16; j < sg.y; j += 16) acc += Z[csr[j]];
    }
#pragma unroll
    for (int off = 8; off > 0; off >>= 1) acc += __shfl_down(acc, off);
    float accB = __shfl(acc, lane + 16);
    if (sub == 0 && d < N)
        out[d] = outacc[d] + dinv1[d] * acc + dinv2[d] * accB;
}

// ================= host =================
static inline char* carve(char*& p, size_t bytes) {
    char* r = p;
    p += (bytes + 255) & ~(size_t)255;
    return r;
}

extern "C" void kernel_launch(void* const* d_in, const int* in_sizes, int n_in,
                              void* d_out, int out_size, void* d_ws, size_t ws_size,
                              hipStream_t stream) {
    const float* x    = (const float*)d_in[0];
    const int*   ei1  = (const int*)d_in[1];
    const int*   ei2  = (const int*)d_in[2];
    const float* W_in = (const float*)d_in[3];  const float* b_in = (const float*)d_in[4];
    const float* W11  = (const float*)d_in[5];
    const float* b11  = (const float*)d_in[6];
    const float* W12  = (const float*)d_in[7];  const float* b12  = (const float*)d_in[8];
    const float* W21  = (const float*)d_in[9];  const float* b21  = (const float*)d_in[10];
    const float* W22  = (const float*)d_in[11]; const float* b22  = (const float*)d_in[12];
    const float* W31  = (const float*)d_in[13]; const float* b31  = (const float*)d_in[14];
    const float* W32  = (const float*)d_in[15]; const float* b32  = (const float*)d_in[16];
    const float* Wr0  = (const float*)d_in[17]; const float* br0  = (const float*)d_in[18];
    const float* Wr1  = (const float*)d_in[19]; const float* br1  = (const float*)d_in[20];
    const float* Wr2  = (const float*)d_in[21]; const float* br2  = (const float*)d_in[22];
    const float* Wr3  = (const float*)d_in[23]; const float* br3  = (const float*)d_in[24];
    const float* w0   = (const float*)d_in[25];
    const float* w1   = (const float*)d_in[26];
    const float* w2   = (const float*)d_in[27];
    const float* w3   = (const float*)d_in[28];

    const int N  = in_sizes[0] / 64;   // 50000 (fits u16)
    const int E1 = in_sizes[1] / 2;    // 800000
    const int E2 = in_sizes[2] / 2;
    const int Etot = E1 + E2;
    const int N2 = 2 * N;
    const int NB = (N + 127) >> 7;     // 128-node buckets per set
    const int NP = 2 * NB * SLICES;

    char* p = (char*)d_ws;
    float*  dinv1   = (float*)carve(p, (size_t)N * 4);
    float*  dinv2   = (float*)carve(p, (size_t)N * 4);
    int*    pcnt    = (int*)  carve(p, (size_t)NP * 4);          // scanned in place -> poffs
    int*    bendv   = (int*)  carve(p, (size_t)2 * NB * 4);
    u32*    eord    = (u32*)  carve(p, (size_t)Etot * 4);        // packed (r<<7 | c&127)
    int2*   se      = (int2*) carve(p, (size_t)N2 * 8);
    float*  uws     = (float*)carve(p, 1200 * 4);
    float*  z       = (float*)carve(p, (size_t)N2 * 4);
    float*  pr      = (float*)carve(p, (size_t)N * 4);
    float4* sA      = (float4*)carve(p, (size_t)N * 16);
    float4* sB      = (float4*)carve(p, (size_t)N * 16);
    u16*    csr     = (u16*)  carve(p, (size_t)Etot * 2);
    float*  s1p     = (float*)carve(p, (size_t)N * 8 * 4);       // UNSCALED source payloads
    float*  s2p     = (float*)carve(p, (size_t)N * 8 * 4);
    float*  outacc  = (float*)carve(p, (size_t)N * 4);
    u32*    gbase   = (u32*)  carve(p, 4);
    float*  c2v = uws + 257;
    float*  z1 = z, *z2 = z + N;
    (void)ws_size; (void)n_in; (void)out_size;

    const int B = 256;
    dim3 blk(B);
    int gMM  = (N + 63) / 64;
    int gG   = (int)(((long long)N * 64 + B - 1) / B);             // 1 dest/wave (gatherP)
    int gG2  = (int)(((long long)((N + 1) / 2) * 64 + B - 1) / B); // 2 dests/wave (gatherS/3)

    // ---- side stream for the CSR-independent branch (uprep -> mmR0), graph-capture fork ----
    static hipStream_t s2 = nullptr;
    static hipEvent_t evF = nullptr, evJ = nullptr;
    static bool s2ok = false;
    if (!s2 && !s2ok) {
        if (hipStreamCreateWithFlags(&s2, hipStreamNonBlocking) == hipSuccess &&
            hipEventCreateWithFlags(&evF, hipEventDisableTiming) == hipSuccess &&
            hipEventCreateWithFlags(&evJ, hipEventDisableTiming) == hipSuccess) {
            s2ok = true;
        } else {
            s2 = nullptr;
            (void)hipGetLastError();
        }
    }

    hipStream_t mmStream = stream;
    if (s2ok) {
        hipEventRecord(evF, stream);
        hipStreamWaitEvent(s2, evF, 0);
        mmStream = s2;
    }

    // Branch A (s2 or serial): uprep -> mmR0 (independent of CSR build)
    uprep<<<1, blk, 0, mmStream>>>(W11, W12, W21, W22, W31, W32,
                                   b11, b12, b21, b22, b31, b32,
                                   Wr1, Wr2, Wr3, br3, uws);
    mmR0<<<gMM, blk, 0, mmStream>>>(x, W_in, b_in, s1p, s2p,
                                    Wr0, br0, br1, br2, w0, w1, w2, w3, uws, outacc, N);
    if (s2ok) hipEventRecord(evJ, s2);

    // Branch B (main): CSR build chain
    histU<<<TWOS + 1, blk, 0, stream>>>(ei1, ei2, pcnt, gbase, NB, E1, E2);
    scanB<<<2 * NB, blk, 0, stream>>>(pcnt, bendv, gbase, 2 * NB);
    part<<<TWOS, blk, 0, stream>>>(ei1, ei2, pcnt, eord, NB, E1, E2);
    fill3<<<2 * NB, blk, 0, stream>>>(eord, pcnt, bendv, se, csr, dinv1, dinv2, N, NB);

    if (s2ok) hipStreamWaitEvent(stream, evJ, 0);

    // Join: gathers need both branches
    gatherP<<<gG, blk, 0, stream>>>(se, csr, s1p, s2p, dinv1, dinv2, uws, sA, sB, pr, N);
    gatherS<<<gG2, blk, 0, stream>>>(se, csr, sA, sB, pr, dinv1, dinv2,
                                     w1, w2, w3, c2v, outacc, z1, z2, N);
    gather3<<<gG2, blk, 0, stream>>>(se, csr, z1, z2, dinv1, dinv2, outacc, (float*)d_out, N);
}

// Round 13
// 233.139 us; speedup vs baseline: 1.3306x; 1.3306x over previous
//
#include <hip/hip_runtime.h>
#include <cstdint>
#include <cstddef>

typedef unsigned short u16;
typedef unsigned int u32;
typedef __attribute__((ext_vector_type(8))) short shortx8;
typedef __attribute__((ext_vector_type(4))) float floatx4;

#define SLICES 128
#define TWOS   (2 * SLICES)
#define F3CAP  5120

__device__ __forceinline__ u16 f2b(float f) {
    u32 b = __float_as_uint(f);
    b += 0x7fffu + ((b >> 16) & 1u);   // RNE
    return (u16)(b >> 16);
}

// ================= uprep body: all weight-space pushdown precompute =================
// uw layout (floats):
//   [0,128) u31; [128,256) u32; [256] c3; [257,260) c2v;
//   [260,708) m1c[7][64]; [708,1156) m2c[7][64]; [1156,1163) C[7]
__device__ void uprep_body(const float* __restrict__ W11, const float* __restrict__ W12,
                           const float* __restrict__ W21, const float* __restrict__ W22,
                           const float* __restrict__ W31, const float* __restrict__ W32,
                           const float* __restrict__ b11, const float* __restrict__ b12,
                           const float* __restrict__ b21, const float* __restrict__ b22,
                           const float* __restrict__ b31, const float* __restrict__ b32,
                           const float* __restrict__ Wr1, const float* __restrict__ Wr2,
                           const float* __restrict__ Wr3, const float* __restrict__ br3,
                           float* __restrict__ uw, float* H /* [6][128] LDS */) {
    int t = threadIdx.x;
    if (t < 128) {
        float a = 0.f, b = 0.f;
        for (int c = 0; c < 64; ++c) {
            a = fmaf(W31[t * 64 + c], Wr3[c], a);
            b = fmaf(W32[t * 64 + c], Wr3[64 + c], b);
        }
        uw[t] = a;
        uw[128 + t] = b;
    }
    __syncthreads();
    for (int it = t; it < 768; it += 256) {
        int v = it >> 7;
        int k = it & 127;
        const float* W = (v < 3) ? W21 : W22;
        const float* s;
        switch (v % 3) { case 0: s = Wr2; break; case 1: s = uw; break; default: s = uw + 128; }
        int so = (v < 3) ? 0 : 64;
        float acc = 0.f;
        for (int c = 0; c < 64; ++c) acc = fmaf(W[k * 64 + c], s[so + c], acc);
        H[v * 128 + k] = acc;
    }
    __syncthreads();
    for (int it = t; it < 7 * 64; it += 256) {
        int j = it >> 6, i = it & 63;
        float a1 = 0.f, a2 = 0.f;
        if (j == 0) {
            for (int c = 0; c < 64; ++c) {
                a1 = fmaf(W11[i * 64 + c], Wr1[c], a1);
                a2 = fmaf(W12[i * 64 + c], Wr1[64 + c], a2);
            }
        } else {
            const float* h = &H[(j - 1) * 128];
            for (int c = 0; c < 64; ++c) {
                a1 = fmaf(W11[i * 64 + c], h[c], a1);
                a2 = fmaf(W12[i * 64 + c], h[64 + c], a2);
            }
        }
        uw[260 + j * 64 + i] = a1;
        uw[708 + j * 64 + i] = a2;
    }
    if (t < 64) {
        float bb1 = b11[t], bb2 = b12[t];
        float r;
#define REDW(VAL, IDX)                                                  \
        { r = (VAL);                                                    \
          for (int o = 32; o > 0; o >>= 1) r += __shfl_down(r, o);      \
          if (t == 0) uw[IDX] = r; }
        REDW(bb1 * Wr1[t] + bb2 * Wr1[64 + t], 1156)
        REDW(bb1 * H[0 * 128 + t] + bb2 * H[0 * 128 + 64 + t], 1157)
        REDW(bb1 * H[1 * 128 + t] + bb2 * H[1 * 128 + 64 + t], 1158)
        REDW(bb1 * H[2 * 128 + t] + bb2 * H[2 * 128 + 64 + t], 1159)
        REDW(bb1 * H[3 * 128 + t] + bb2 * H[3 * 128 + 64 + t], 1160)
        REDW(bb1 * H[4 * 128 + t] + bb2 * H[4 * 128 + 64 + t], 1161)
        REDW(bb1 * H[5 * 128 + t] + bb2 * H[5 * 128 + 64 + t], 1162)
        float c1 = b21[t], c2 = b22[t];
        REDW(c1 * Wr2[t] + c2 * Wr2[64 + t], 257)
        REDW(c1 * uw[t] + c2 * uw[64 + t], 258)
        REDW(c1 * uw[128 + t] + c2 * uw[192 + t], 259)
        REDW(b31[t] * Wr3[t] + b32[t] * Wr3[64 + t], 256)
        if (t == 0) uw[256] += br3[0];
#undef REDW
    }
}

// ================= histU: per-(bucket,slice) histogram + uprep rider + gbase init ==========
__global__ __launch_bounds__(256) void histU(const int* __restrict__ ei1, const int* __restrict__ ei2,
                                             int* __restrict__ pcnt,
                                             const float* __restrict__ W11, const float* __restrict__ W12,
                                             const float* __restrict__ W21, const float* __restrict__ W22,
                                             const float* __restrict__ W31, const float* __restrict__ W32,
                                             const float* __restrict__ b11, const float* __restrict__ b12,
                                             const float* __restrict__ b21, const float* __restrict__ b22,
                                             const float* __restrict__ b31, const float* __restrict__ b32,
                                             const float* __restrict__ Wr1, const float* __restrict__ Wr2,
                                             const float* __restrict__ Wr3, const float* __restrict__ br3,
                                             float* __restrict__ uw, u32* __restrict__ gbase,
                                             int NB, int E1, int E2) {
    __shared__ u32 h[512];
    __shared__ float H[6 * 128];
    int bid = blockIdx.x;
    if (bid == TWOS) {
        uprep_body(W11, W12, W21, W22, W31, W32, b11, b12, b21, b22, b31, b32,
                   Wr1, Wr2, Wr3, br3, uw, H);
        return;
    }
    if (bid == TWOS + 1) {
        if (threadIdx.x == 0) *gbase = 0;
        return;
    }
    int set = bid >> 7;
    int s = bid & (SLICES - 1);
    const int* col = set ? ei2 + E2 : ei1 + E1;
    int E = set ? E2 : E1;
    for (int i = threadIdx.x; i < NB; i += 256) h[i] = 0;
    __syncthreads();
    int esz = (E + SLICES - 1) / SLICES;
    int e0 = s * esz, e1 = min(e0 + esz, E);
    for (int e = e0 + threadIdx.x; e < e1; e += 256)
        atomicAdd(&h[col[e] >> 7], 1u);
    __syncthreads();
    for (int b = threadIdx.x; b < NB; b += 256)
        pcnt[(size_t)(set * NB + b) * SLICES + s] = (int)h[b];
}

// ====== scanB: per-bucket scan of 128 slice counts + atomic region base ======
__global__ __launch_bounds__(256) void scanB(int* __restrict__ pcnt, int* __restrict__ bend,
                                             u32* __restrict__ gbase, int NBtot) {
    __shared__ int sc[SLICES];
    __shared__ u32 baseSh;
    int bid = blockIdx.x;
    if (bid >= NBtot) return;
    int t = threadIdx.x;
    int v = 0;
    if (t < SLICES) { v = pcnt[(size_t)bid * SLICES + t]; sc[t] = v; }
    __syncthreads();
    for (int off = 1; off < SLICES; off <<= 1) {
        int u = (t < SLICES && t >= off) ? sc[t - off] : 0;
        __syncthreads();
        if (t < SLICES) sc[t] += u;
        __syncthreads();
    }
    if (t == 0) {
        u32 total = (u32)sc[SLICES - 1];
        u32 base = atomicAdd(gbase, total);
        baseSh = base;
        bend[bid] = (int)(base + total);
    }
    __syncthreads();
    if (t < SLICES) pcnt[(size_t)bid * SLICES + t] = (int)(baseSh + (u32)(sc[t] - v));
}

// ================= partMM: mmR0 blocks first, then radix-partition blocks =================
__global__ __launch_bounds__(256) void partMM(const float* __restrict__ x,
                                              const float* __restrict__ W_in,
                                              const float* __restrict__ b_in,
                                              float* __restrict__ s1p,
                                              float* __restrict__ s2p,
                                              const float* __restrict__ Wr0,
                                              const float* __restrict__ br0,
                                              const float* __restrict__ br1,
                                              const float* __restrict__ br2,
                                              const float* __restrict__ w0,
                                              const float* __restrict__ w1,
                                              const float* __restrict__ w2,
                                              const float* __restrict__ w3,
                                              const float* __restrict__ uw,
                                              float* __restrict__ outacc,
                                              const int* __restrict__ ei1, const int* __restrict__ ei2,
                                              const int* __restrict__ poffs, u32* __restrict__ eord,
                                              int n, int gMM, int NB, int E1, int E2) {
    constexpr int LDA = 72;
    __shared__ u16 As[64 * LDA];
    __shared__ u16 W0s[64 * LDA];
    __shared__ float Msw[64][17];
    __shared__ u32 curL[512];

    if ((int)blockIdx.x >= gMM) {
        // ---- part role ----
        int pb = blockIdx.x - gMM;
        int set = pb >> 7;
        int s = pb & (SLICES - 1);
        const int* rows = set ? ei2 : ei1;
        int E = set ? E2 : E1;
        const int* cols = rows + E;
        for (int b = threadIdx.x; b < NB; b += 256)
            curL[b] = (u32)poffs[(size_t)(set * NB + b) * SLICES + s];
        __syncthreads();
        int esz = (E + SLICES - 1) / SLICES;
        int e0 = s * esz, e1 = min(e0 + esz, E);
        for (int e = e0 + threadIdx.x; e < e1; e += 256) {
            int c = cols[e];
            u32 pos = atomicAdd(&curL[c >> 7], 1u);
            eord[pos] = ((u32)rows[e] << 7) | (u32)(c & 127);
        }
        return;
    }

    // ---- mmR0 role ----
    const int tid = threadIdx.x;
    const int r0 = blockIdx.x * 64;

    for (int idx = tid; idx < 64 * 16; idx += 256) {
        int r = idx >> 4, q4 = (idx & 15) * 4;
        int gr = r0 + r;
        float4 v = {0, 0, 0, 0};
        if (gr < n) v = *(const float4*)&x[(size_t)gr * 64 + q4];
        ushort4 o = {f2b(v.x), f2b(v.y), f2b(v.z), f2b(v.w)};
        *(ushort4*)&As[r * LDA + q4] = o;
    }
    for (int idx = tid; idx < 16 * 64; idx += 256) {
        int k = idx >> 4, qc = idx & 15;
        float4 a = *(const float4*)&W_in[k * 64 + 4 * qc];
        W0s[(4*qc+0) * LDA + k] = f2b(a.x); W0s[(4*qc+1) * LDA + k] = f2b(a.y);
        W0s[(4*qc+2) * LDA + k] = f2b(a.z); W0s[(4*qc+3) * LDA + k] = f2b(a.w);
    }
    for (int idx = tid; idx < 896; idx += 256) {
        int mat = idx / 448, rem = idx % 448;
        Msw[rem & 63][mat * 8 + (rem >> 6)] = uw[260 + idx];
    }
    for (int idx = tid; idx < 128; idx += 256) {
        Msw[idx & 63][(idx >> 6) * 8 + 7] = 0.f;
    }
    __syncthreads();

    const int wave = tid >> 6;
    const int lane = tid & 63;
    const int m = lane & 15;
    const int ko = (lane >> 4) * 8;
    floatx4 z4 = {0.f, 0.f, 0.f, 0.f};
    floatx4 accR[4] = {z4, z4, z4, z4};

#pragma unroll
    for (int kc = 0; kc < 64; kc += 32) {
        shortx8 af = *(shortx8*)&As[(wave * 16 + m) * LDA + kc + ko];
#pragma unroll
        for (int nt = 0; nt < 4; ++nt) {
            shortx8 bf = *(shortx8*)&W0s[(nt * 16 + m) * LDA + kc + ko];
            accR[nt] = __builtin_amdgcn_mfma_f32_16x16x32_bf16(af, bf, accR[nt], 0, 0, 0);
        }
    }

    float bv[4], wr0[4];
#pragma unroll
    for (int nt = 0; nt < 4; ++nt) {
        bv[nt] = b_in[nt * 16 + m];
        wr0[nt] = Wr0[nt * 16 + m];
    }
    const int lrow = wave * 16 + (lane >> 4) * 4;
    float W0c = w0[0];
    float CONST = W0c * br0[0] + w1[0] * (br1[0] + uw[1156]) + w2[0] * br2[0] + w3[0] * uw[256];
#pragma unroll
    for (int rg = 0; rg < 4; ++rg) {
        int gr = r0 + lrow + rg;
        float p = 0.f;
#pragma unroll
        for (int nt = 0; nt < 4; ++nt) {
            float v = fmaxf(accR[nt][rg] + bv[nt], 0.f);
            As[(lrow + rg) * LDA + nt * 16 + m] = f2b(v);   // R0 back into LDS (wave-private)
            p = fmaf(v, wr0[nt], p);
        }
#pragma unroll
        for (int off = 8; off > 0; off >>= 1) p += __shfl_down(p, off);
        if (m == 0 && gr < n) outacc[gr] = W0c * p + CONST;
    }
    // No barrier: each wave reads only its own 16 rows of As below.
    {
        int prow = lane & 15;
        int q = lane >> 4;
        int row = wave * 16 + prow;
        const int cb = (q >> 1) * 8 + (q & 1) * 4;
        float p0 = 0.f, p1 = 0.f, p2 = 0.f, p3 = 0.f;
#pragma unroll
        for (int kc = 0; kc < 64; kc += 8) {
            shortx8 rv = *(shortx8*)&As[row * LDA + kc];
#pragma unroll
            for (int tt = 0; tt < 8; ++tt) {
                float f = __uint_as_float(((u32)(u16)rv[tt]) << 16);
                p0 = fmaf(f, Msw[kc + tt][cb + 0], p0);
                p1 = fmaf(f, Msw[kc + tt][cb + 1], p1);
                p2 = fmaf(f, Msw[kc + tt][cb + 2], p2);
                p3 = fmaf(f, Msw[kc + tt][cb + 3], p3);
            }
        }
        int gr = r0 + row;
        if (gr < n) {
            float* dst = ((q < 2) ? s1p : s2p) + (size_t)gr * 8 + (q & 1) * 4;
            *(float4*)dst = make_float4(p0, p1, p2, p3);   // UNSCALED; dinv[src] in gatherP
        }
    }
}

// ================= fill3: per-bucket count/place -> se(int2), dinv, u16 csr =================
__global__ __launch_bounds__(256) void fill3(const u32* __restrict__ eord,
                                             const int* __restrict__ poffs,
                                             const int* __restrict__ bend,
                                             int2* __restrict__ se,
                                             u16* __restrict__ csr,
                                             float* __restrict__ d1, float* __restrict__ d2,
                                             int N, int NB) {
    __shared__ u32 cacheE[F3CAP];
    __shared__ u32 cnt[128];
    __shared__ int sc[128];
    __shared__ u32 cur[128];
    int bid = blockIdx.x;
    int set = bid >= NB;
    int bucket = set ? bid - NB : bid;
    if (threadIdx.x < 128) cnt[threadIdx.x] = 0;
    __syncthreads();
    int s0 = poffs[(size_t)bid * SLICES];
    int s1 = bend[bid];
    for (int j = s0 + threadIdx.x; j < s1; j += 256) {
        u32 e = eord[j];
        int o = j - s0;
        if (o < F3CAP) cacheE[o] = e;
        atomicAdd(&cnt[e & 127], 1u);
    }
    __syncthreads();
    if (threadIdx.x < 128) sc[threadIdx.x] = (int)cnt[threadIdx.x];
    __syncthreads();
    for (int off = 1; off < 128; off <<= 1) {
        int u = (threadIdx.x < 128 && threadIdx.x >= off) ? sc[threadIdx.x - off] : 0;
        __syncthreads();
        if (threadIdx.x < 128) sc[threadIdx.x] += u;
        __syncthreads();
    }
    if (threadIdx.x < 128) {
        u32 st = (u32)s0 + (u32)(sc[threadIdx.x] - (int)cnt[threadIdx.x]);  // exclusive
        cur[threadIdx.x] = st;
        int bin = bucket * 128 + threadIdx.x;
        if (bin < N) {
            se[set * N + bin] = make_int2((int)st, (int)(st + (int)cnt[threadIdx.x]));
            u32 d = cnt[threadIdx.x];
            float v = d > 0 ? rsqrtf((float)d) : 0.f;
            if (set) d2[bin] = v;
            else d1[bin] = v;
        }
    }
    __syncthreads();
    for (int j = s0 + threadIdx.x; j < s1; j += 256) {
        int o = j - s0;
        u32 e = (o < F3CAP) ? cacheE[o] : eord[j];
        u32 pos = atomicAdd(&cur[e & 127], 1u);
        csr[pos] = (u16)(e >> 7);
    }
}

// ========= gatherP: both-set payload gather + epilogue (1 dest/wave; dinv[src] per edge) =======
__global__ __launch_bounds__(256) void gatherP(const int2* __restrict__ se,
                                               const u16* __restrict__ csr,
                                               const float* __restrict__ s1p,
                                               const float* __restrict__ s2p,
                                               const float* __restrict__ dinv1,
                                               const float* __restrict__ dinv2,
                                               const float* __restrict__ uw,
                                               float4* __restrict__ sA,
                                               float4* __restrict__ sB,
                                               float* __restrict__ pr, int N) {
    int d = (blockIdx.x * blockDim.x + threadIdx.x) >> 6;
    int lane = threadIdx.x & 63;
    if (d >= N) return;
    int half = lane >> 5;
    int slot = (lane & 31) >> 1;
    int part = lane & 1;
    int base = half ? N : 0;
    int2 sg = se[base + d];
    const float* S = half ? s2p : s1p;
    const float* D = half ? dinv2 : dinv1;
    float ax = 0.f, ay = 0.f, az = 0.f, aw = 0.f;
    for (int j = sg.x + slot; j < sg.y; j += 16) {
        u32 src = csr[j];
        float w = D[src];
        float4 pv = *(const float4*)&S[(size_t)src * 8 + part * 4];
        ax = fmaf(w, pv.x, ax); ay = fmaf(w, pv.y, ay);
        az = fmaf(w, pv.z, az); aw = fmaf(w, pv.w, aw);
    }
#pragma unroll
    for (int off = 2; off <= 16; off <<= 1) {
        ax += __shfl_down(ax, off);
        ay += __shfl_down(ay, off);
        az += __shfl_down(az, off);
        aw += __shfl_down(aw, off);
    }
    float bx = __shfl(ax, lane + 32);
    float by = __shfl(ay, lane + 32);
    float bz = __shfl(az, lane + 32);
    float bw = __shfl(aw, lane + 32);
    if (lane < 2) {
        float da = dinv1[d], db = dinv2[d];
        float d0 = da * ax + db * bx;
        float d1 = da * ay + db * by;
        float d2 = da * az + db * bz;
        float d3 = da * aw + db * bw;
        const float* C = uw + 1156;
        if (lane == 0) {
            pr[d] = d0;
            sA[d] = make_float4(da * (d1 + C[1]), da * (d2 + C[2]), da * (d3 + C[3]), 0.f);
        } else {
            sB[d] = make_float4(db * (d0 + C[4]), db * (d1 + C[5]), db * (d2 + C[6]), 0.f);
        }
    }
}

// ================= gatherS: 2 destinations per wave; 16 lanes per (dest,set) =================
__global__ __launch_bounds__(256) void gatherS(const int2* __restrict__ se,
                                               const u16* __restrict__ csr,
                                               const float4* __restrict__ sA,
                                               const float4* __restrict__ sB,
                                               const float* __restrict__ pr,
                                               const float* __restrict__ dinv1,
                                               const float* __restrict__ dinv2,
                                               const float* __restrict__ w1,
                                               const float* __restrict__ w2,
                                               const float* __restrict__ w3,
                                               const float* __restrict__ c2v,
                                               float* __restrict__ outacc,
                                               float* __restrict__ z1, float* __restrict__ z2, int N) {
    int wid = (blockIdx.x * blockDim.x + threadIdx.x) >> 6;
    int lane = threadIdx.x & 63;
    int g = lane >> 5;
    int sub = lane & 31;
    int set = sub >> 4;
    int l16 = sub & 15;
    int d = wid * 2 + g;
    float p = 0.f, q1 = 0.f, q2 = 0.f;
    if (d < N) {
        int base = set ? N : 0;
        int2 sg = se[base + d];
        const float4* S = set ? sB : sA;
        for (int j = sg.x + l16; j < sg.y; j += 16) {
            float4 s = S[csr[j]];
            p += s.x; q1 += s.y; q2 += s.z;
        }
    }
#pragma unroll
    for (int off = 8; off > 0; off >>= 1) {
        p += __shfl_down(p, off); q1 += __shfl_down(q1, off); q2 += __shfl_down(q2, off);
    }
    float pB  = __shfl(p,  lane + 16);
    float qB1 = __shfl(q1, lane + 16);
    float qB2 = __shfl(q2, lane + 16);
    if (sub == 0 && d < N) {
        float da = dinv1[d], db = dinv2[d];
        float pp  = da * p  + db * pB;
        float qq1 = da * q1 + db * qB1;
        float qq2 = da * q2 + db * qB2;
        float W3 = w3[0];
        outacc[d] += w1[0] * pr[d] + w2[0] * (pp + c2v[0]);
        z1[d] = da * (W3 * (qq1 + c2v[1]));
        z2[d] = db * (W3 * (qq2 + c2v[2]));
    }
}

// ================= gather3: 2 destinations per wave; 16 lanes per (dest,set) =================
__global__ __launch_bounds__(256) void gather3(const int2* __restrict__ se,
                                               const u16* __restrict__ csr,
                                               const float* __restrict__ z1,
                                               const float* __restrict__ z2,
                                               const float* __restrict__ dinv1,
                                               const float* __restrict__ dinv2,
                                               const float* __restrict__ outacc,
                                               float* __restrict__ out, int N) {
    int wid = (blockIdx.x * blockDim.x + threadIdx.x) >> 6;
    int lane = threadIdx.x & 63;
    int g = lane >> 5;
    int sub = lane & 31;
    int set = sub >> 4;
    int l16 = sub & 15;
    int d = wid * 2 + g;
    float acc = 0.f;
    if (d < N) {
        int base = set ? N : 0;
        int2 sg = se[base + d];
        const float* Z = set ? z2 : z1;
        for (int j = sg.x + l16; j < sg.y; j += 16) acc += Z[csr[j]];
    }
#pragma unroll
    for (int off = 8; off > 0; off >>= 1) acc += __shfl_down(acc, off);
    float accB = __shfl(acc, lane + 16);
    if (sub == 0 && d < N)
        out[d] = outacc[d] + dinv1[d] * acc + dinv2[d] * accB;
}

// ================= host =================
static inline char* carve(char*& p, size_t bytes) {
    char* r = p;
    p += (bytes + 255) & ~(size_t)255;
    return r;
}

extern "C" void kernel_launch(void* const* d_in, const int* in_sizes, int n_in,
                              void* d_out, int out_size, void* d_ws, size_t ws_size,
                              hipStream_t stream) {
    const float* x    = (const float*)d_in[0];
    const int*   ei1  = (const int*)d_in[1];
    const int*   ei2  = (const int*)d_in[2];
    const float* W_in = (const float*)d_in[3];  const float* b_in = (const float*)d_in[4];
    const float* W11  = (const float*)d_in[5];
    const float* b11  = (const float*)d_in[6];
    const float* W12  = (const float*)d_in[7];  const float* b12  = (const float*)d_in[8];
    const float* W21  = (const float*)d_in[9];  const float* b21  = (const float*)d_in[10];
    const float* W22  = (const float*)d_in[11]; const float* b22  = (const float*)d_in[12];
    const float* W31  = (const float*)d_in[13]; const float* b31  = (const float*)d_in[14];
    const float* W32  = (const float*)d_in[15]; const float* b32  = (const float*)d_in[16];
    const float* Wr0  = (const float*)d_in[17]; const float* br0  = (const float*)d_in[18];
    const float* Wr1  = (const float*)d_in[19]; const float* br1  = (const float*)d_in[20];
    const float* Wr2  = (const float*)d_in[21]; const float* br2  = (const float*)d_in[22];
    const float* Wr3  = (const float*)d_in[23]; const float* br3  = (const float*)d_in[24];
    const float* w0   = (const float*)d_in[25];
    const float* w1   = (const float*)d_in[26];
    const float* w2   = (const float*)d_in[27];
    const float* w3   = (const float*)d_in[28];

    const int N  = in_sizes[0] / 64;   // 50000 (fits u16)
    const int E1 = in_sizes[1] / 2;    // 800000
    const int E2 = in_sizes[2] / 2;
    const int Etot = E1 + E2;
    const int N2 = 2 * N;
    const int NB = (N + 127) >> 7;     // 128-node buckets per set
    const int NP = 2 * NB * SLICES;

    char* p = (char*)d_ws;
    float*  dinv1   = (float*)carve(p, (size_t)N * 4);
    float*  dinv2   = (float*)carve(p, (size_t)N * 4);
    int*    pcnt    = (int*)  carve(p, (size_t)NP * 4);          // scanned in place -> poffs
    int*    bendv   = (int*)  carve(p, (size_t)2 * NB * 4);
    u32*    eord    = (u32*)  carve(p, (size_t)Etot * 4);        // packed (r<<7 | c&127)
    int2*   se      = (int2*) carve(p, (size_t)N2 * 8);
    float*  uws     = (float*)carve(p, 1200 * 4);
    float*  z       = (float*)carve(p, (size_t)N2 * 4);
    float*  pr      = (float*)carve(p, (size_t)N * 4);
    float4* sA      = (float4*)carve(p, (size_t)N * 16);
    float4* sB      = (float4*)carve(p, (size_t)N * 16);
    u16*    csr     = (u16*)  carve(p, (size_t)Etot * 2);
    float*  s1p     = (float*)carve(p, (size_t)N * 8 * 4);       // UNSCALED source payloads
    float*  s2p     = (float*)carve(p, (size_t)N * 8 * 4);
    float*  outacc  = (float*)carve(p, (size_t)N * 4);
    u32*    gbase   = (u32*)  carve(p, 4);
    float*  c2v = uws + 257;
    float*  z1 = z, *z2 = z + N;
    (void)ws_size; (void)n_in; (void)out_size;

    const int B = 256;
    dim3 blk(B);
    int gMM  = (N + 63) / 64;
    int gG   = (int)(((long long)N * 64 + B - 1) / B);             // 1 dest/wave (gatherP)
    int gG2  = (int)(((long long)((N + 1) / 2) * 64 + B - 1) / B); // 2 dests/wave (gatherS/3)

    // 7-launch pipeline (single in-order stream; proven best packaging)
    histU<<<TWOS + 2, blk, 0, stream>>>(ei1, ei2, pcnt,
                                        W11, W12, W21, W22, W31, W32,
                                        b11, b12, b21, b22, b31, b32,
                                        Wr1, Wr2, Wr3, br3, uws, gbase, NB, E1, E2);
    scanB<<<2 * NB, blk, 0, stream>>>(pcnt, bendv, gbase, 2 * NB);
    partMM<<<gMM + TWOS, blk, 0, stream>>>(x, W_in, b_in, s1p, s2p,
                                           Wr0, br0, br1, br2, w0, w1, w2, w3, uws, outacc,
                                           ei1, ei2, pcnt, eord, N, gMM, NB, E1, E2);
    fill3<<<2 * NB, blk, 0, stream>>>(eord, pcnt, bendv, se, csr, dinv1, dinv2, N, NB);
    gatherP<<<gG, blk, 0, stream>>>(se, csr, s1p, s2p, dinv1, dinv2, uws, sA, sB, pr, N);
    gatherS<<<gG2, blk, 0, stream>>>(se, csr, sA, sB, pr, dinv1, dinv2,
                                     w1, w2, w3, c2v, outacc, z1, z2, N);
    gather3<<<gG2, blk, 0, stream>>>(se, csr, z1, z2, dinv1, dinv2, outacc, (float*)d_out, N);
}